// Round 3
// baseline (159.547 us; speedup 1.0000x reference)
//
#include <hip/hip_runtime.h>

#define VOCAB 50257
#define EMBED 256
#define OUT 5
#define BATCH 512
#define SEQ 512
#define PADO 8    // padded embW row stride (32 B): aligned float4+float gathers
#define NBLK 512  // 2 blocks/CU at 256 threads -> trivially all co-resident

// Single fused kernel, regular launch + homemade device-scope barrier
// (hipLaunchCooperativeKernel is rejected under the harness's graph capture —
//  round-2 failure: output stayed 0, absmax == ln(5)).
//
//   phase 1: embW[v][o] = dot(emb[v,:], W[o,:])   (grid-stride, 4 rows/wave,
//            16 lanes/row, W held in registers, no LDS)
//   full barrier (cnt[0]: release-add arrival, acquire-spin)
//   phase 2: block b = sample b: ragged-sum embW gathers -> logits ->
//            log-softmax -> per-sample NLL -> losses[b]
//   arrival-only barrier (cnt[1]); non-zero blocks exit
//   phase 3: block 0 spins to 512, deterministic mean over losses
__global__ __launch_bounds__(256) void k_fused(const int* __restrict__ x,
                                               const int* __restrict__ lengths,
                                               const int* __restrict__ y,
                                               const float* __restrict__ emb,
                                               const float* __restrict__ W,
                                               const float* __restrict__ bias,
                                               unsigned* __restrict__ cnt,   // cnt[0..1] pre-zeroed
                                               float* __restrict__ embW,
                                               float* __restrict__ losses,
                                               float* __restrict__ out) {
    __shared__ float red[4][OUT];
    __shared__ float red2[4];

    const int tid  = threadIdx.x;
    const int lane = tid & 63;
    const int sub  = lane >> 4;   // which row of the quad this lane works on
    const int col  = lane & 15;   // 16-float chunk within the row

    // ---- phase 1: embW build ----
    {
        // Per-lane register copy of W chunk: w[o][c] = W[o][col*16 + c*4 .. +3]
        float4 w[OUT][4];
#pragma unroll
        for (int o = 0; o < OUT; ++o)
#pragma unroll
            for (int c = 0; c < 4; ++c)
                w[o][c] = *(const float4*)(W + o * EMBED + col * 16 + c * 4);

        const int waveId = (int)((blockIdx.x * 256u + tid) >> 6);
        const int nWaves = NBLK * 4;          // 2048 waves
        const int nQuad  = (VOCAB + 3) / 4;   // 12565 row-quads

        for (int q = waveId; q < nQuad; q += nWaves) {
            const int v = q * 4 + sub;
            float p[OUT] = {0.f, 0.f, 0.f, 0.f, 0.f};
            if (v < VOCAB) {
                const float* row = emb + (size_t)v * EMBED + col * 16;
#pragma unroll
                for (int c = 0; c < 4; ++c) {
                    const float4 e = *(const float4*)(row + c * 4);
#pragma unroll
                    for (int o = 0; o < OUT; ++o)
                        p[o] += e.x * w[o][c].x + e.y * w[o][c].y +
                                e.z * w[o][c].z + e.w * w[o][c].w;
                }
            }
            // Reduce within each 16-lane group (4 steps x 5 outputs).
#pragma unroll
            for (int o = 0; o < OUT; ++o) {
#pragma unroll
                for (int off = 8; off > 0; off >>= 1)
                    p[o] += __shfl_down(p[o], off, 16);
            }
            if (col == 0 && v < VOCAB) {
                float* dst = embW + (size_t)v * PADO;   // 32 B-aligned
                *(float4*)dst = make_float4(p[0], p[1], p[2], p[3]);
                dst[4] = p[4];
            }
        }
    }

    // ---- full grid barrier #1 (all embW visible before any gather) ----
    __syncthreads();
    if (tid == 0) {
        __threadfence();  // belt-and-suspenders agent fence
        __hip_atomic_fetch_add(&cnt[0], 1u, __ATOMIC_RELEASE,
                               __HIP_MEMORY_SCOPE_AGENT);
        while (__hip_atomic_load(&cnt[0], __ATOMIC_ACQUIRE,
                                 __HIP_MEMORY_SCOPE_AGENT) < (unsigned)NBLK) {
            __builtin_amdgcn_s_sleep(1);
        }
    }
    __syncthreads();

    // ---- phase 2: per-sample pooling + NLL (block b = sample b) ----
    {
        const int b   = blockIdx.x;
        const int len = lengths[b];

        const int2 tk = ((const int2*)(x + (size_t)b * SEQ))[tid];

        float acc[OUT] = {0.f, 0.f, 0.f, 0.f, 0.f};
        if (2 * tid < len) {
            const float* r = embW + (size_t)tk.x * PADO;
            const float4 a = *(const float4*)r;
            const float a4 = r[4];
            acc[0] += a.x; acc[1] += a.y; acc[2] += a.z; acc[3] += a.w; acc[4] += a4;
        }
        if (2 * tid + 1 < len) {
            const float* r = embW + (size_t)tk.y * PADO;
            const float4 a = *(const float4*)r;
            const float a4 = r[4];
            acc[0] += a.x; acc[1] += a.y; acc[2] += a.z; acc[3] += a.w; acc[4] += a4;
        }

#pragma unroll
        for (int o = 0; o < OUT; ++o) {
#pragma unroll
            for (int off = 32; off > 0; off >>= 1)
                acc[o] += __shfl_down(acc[o], off, 64);
        }

        const int wave = tid >> 6;
        if ((tid & 63) == 0) {
#pragma unroll
            for (int o = 0; o < OUT; ++o) red[wave][o] = acc[o];
        }
        __syncthreads();

        if (tid == 0) {
            float logits[OUT];
            const float inv = 1.0f / (float)len;
#pragma unroll
            for (int o = 0; o < OUT; ++o)
                logits[o] = (red[0][o] + red[1][o] + red[2][o] + red[3][o]) * inv + bias[o];

            float m = logits[0];
#pragma unroll
            for (int o = 1; o < OUT; ++o) m = fmaxf(m, logits[o]);
            float sum = 0.f;
#pragma unroll
            for (int o = 0; o < OUT; ++o) sum += __expf(logits[o] - m);
            const float lse = m + __logf(sum);
            losses[b] = lse - logits[y[b]];

            // arrival (release makes losses[b] visible); no spin except block 0
            __hip_atomic_fetch_add(&cnt[1], 1u, __ATOMIC_RELEASE,
                                   __HIP_MEMORY_SCOPE_AGENT);
        }
    }

    // ---- phase 3: deterministic mean (block 0 only; others exit) ----
    if (blockIdx.x != 0) return;

    if (tid == 0) {
        while (__hip_atomic_load(&cnt[1], __ATOMIC_ACQUIRE,
                                 __HIP_MEMORY_SCOPE_AGENT) < (unsigned)NBLK) {
            __builtin_amdgcn_s_sleep(1);
        }
    }
    __syncthreads();

    float v = losses[tid] + losses[tid + 256];
#pragma unroll
    for (int off = 32; off > 0; off >>= 1)
        v += __shfl_down(v, off, 64);
    if ((tid & 63) == 0) red2[tid >> 6] = v;
    __syncthreads();
    if (tid == 0)
        out[0] = (red2[0] + red2[1] + red2[2] + red2[3]) * (1.0f / (float)BATCH);
}

extern "C" void kernel_launch(void* const* d_in, const int* in_sizes, int n_in,
                              void* d_out, int out_size, void* d_ws, size_t ws_size,
                              hipStream_t stream) {
    const int*   x       = (const int*)d_in[0];
    const int*   lengths = (const int*)d_in[1];
    const int*   y       = (const int*)d_in[2];
    const float* emb     = (const float*)d_in[3];
    const float* W       = (const float*)d_in[4];
    const float* bias    = (const float*)d_in[5];

    // Workspace layout: [cnt(2x u32) | pad to 256 B | embW | losses]
    unsigned* cnt    = (unsigned*)d_ws;
    float*    embW   = (float*)((char*)d_ws + 256);   // VOCAB*PADO floats (~1.6 MB)
    float*    losses = embW + (size_t)VOCAB * PADO;   // BATCH floats
    float*    outp   = (float*)d_out;

    // Counters live in poisoned workspace -> zero them each launch (capturable).
    hipMemsetAsync(cnt, 0, 2 * sizeof(unsigned), stream);

    k_fused<<<NBLK, 256, 0, stream>>>(x, lengths, y, emb, W, bias, cnt, embW,
                                      losses, outp);
}

// Round 4
// 106.633 us; speedup vs baseline: 1.4962x; 1.4962x over previous
//
#include <hip/hip_runtime.h>

#define VOCAB 50257
#define EMBED 256
#define OUT 5
#define BATCH 512
#define SEQ 512
#define NT 1024   // 16 waves per block, one block per sample

// Single kernel, no inter-block dependencies:
//   pooled . W^T  ==  (sum_t emb[x_t]) . W^T   -- so each block gathers raw
// emb rows for its sample, sums them into a lane-distributed 256-float vector,
// dots with W once, applies log-softmax + NLL, and atomicAdd's loss/BATCH.
// No embW table, no grid barrier (round-3's spin barrier cost ~70 us of
// acquire-invalidate storm), no workspace.
__global__ __launch_bounds__(NT) void k_direct(const int* __restrict__ x,
                                               const int* __restrict__ lengths,
                                               const int* __restrict__ y,
                                               const float* __restrict__ emb,
                                               const float* __restrict__ W,
                                               const float* __restrict__ bias,
                                               float* __restrict__ out) {
    const int b    = blockIdx.x;
    const int len  = lengths[b];
    const int tid  = threadIdx.x;
    const int wave = tid >> 6;
    const int lane = tid & 63;

    // Stage this sample's tokens in LDS (coalesced 2 KB) so the gather loop's
    // address chain is LDS-broadcast, not strided scalar-cache misses.
    __shared__ int sx[SEQ];
    if (tid < SEQ) sx[tid] = x[(size_t)b * SEQ + tid];
    __syncthreads();

    // Wave w sums tokens w, w+16, ...; lane owns bytes [lane*16, lane*16+16)
    // of the 1 KB embedding row -> each row is one fully-coalesced wave load.
    float4 acc = make_float4(0.f, 0.f, 0.f, 0.f);
#pragma unroll 4
    for (int s = wave; s < len; s += 16) {
        const float4 r = ((const float4*)(emb + (size_t)sx[s] * EMBED))[lane];
        acc.x += r.x; acc.y += r.y; acc.z += r.z; acc.w += r.w;
    }

    __shared__ float4 sS[NT];   // 16 KB: per-thread partial slices
    sS[tid] = acc;
    __syncthreads();

    if (wave != 0) return;

    // Cross-wave sum: lane l accumulates slice l over all 16 waves.
    float4 S = sS[lane];
#pragma unroll
    for (int w = 1; w < 16; ++w) {
        const float4 t = sS[w * 64 + lane];
        S.x += t.x; S.y += t.y; S.z += t.z; S.w += t.w;
    }

    // logits[o] = dot(S, W[o]) / len + bias[o]
    float p[OUT];
#pragma unroll
    for (int o = 0; o < OUT; ++o) {
        const float4 w4 = ((const float4*)(W + o * EMBED))[lane];
        p[o] = S.x * w4.x + S.y * w4.y + S.z * w4.z + S.w * w4.w;
    }
#pragma unroll
    for (int o = 0; o < OUT; ++o) {
#pragma unroll
        for (int off = 32; off > 0; off >>= 1)
            p[o] += __shfl_down(p[o], off, 64);
    }

    if (lane == 0) {
        const float inv = 1.0f / (float)len;
        float logits[OUT];
#pragma unroll
        for (int o = 0; o < OUT; ++o) logits[o] = p[o] * inv + bias[o];

        float m = logits[0];
#pragma unroll
        for (int o = 1; o < OUT; ++o) m = fmaxf(m, logits[o]);
        float sum = 0.f;
#pragma unroll
        for (int o = 0; o < OUT; ++o) sum += __expf(logits[o] - m);
        const float lse = m + __logf(sum);
        const float loss = lse - logits[y[b]];

        // Mean reduction: out pre-zeroed in kernel_launch; 512 adds total,
        // nondeterminism ~1e-6 << 3.2e-2 threshold.
        atomicAdd(out, loss * (1.0f / (float)BATCH));
    }
}

extern "C" void kernel_launch(void* const* d_in, const int* in_sizes, int n_in,
                              void* d_out, int out_size, void* d_ws, size_t ws_size,
                              hipStream_t stream) {
    const int*   x       = (const int*)d_in[0];
    const int*   lengths = (const int*)d_in[1];
    const int*   y       = (const int*)d_in[2];
    const float* emb     = (const float*)d_in[3];
    const float* W       = (const float*)d_in[4];
    const float* bias    = (const float*)d_in[5];

    hipMemsetAsync(d_out, 0, sizeof(float), stream);   // capturable memset node
    k_direct<<<BATCH, NT, 0, stream>>>(x, lengths, y, emb, W, bias,
                                       (float*)d_out);
}

// Round 5
// 106.158 us; speedup vs baseline: 1.5029x; 1.0045x over previous
//
#include <hip/hip_runtime.h>

#define VOCAB 50257
#define EMBED 256
#define OUT 5
#define BATCH 512
#define SEQ 512
#define PADO 8    // padded embW row stride (32 B): aligned float4+float gathers

// Kernel 1: embW[v][o] = dot(emb[v,:], W[o,:]).
// Persistent 1024 blocks. W held in registers (lane owns the 16-float chunk
// col=lane&15 of every W row). Each wave: 4 vocab rows/iter, 16 lanes/row,
// 4-step width-16 shuffle reduction, no LDS. unroll 2 -> 8 outstanding
// 16 B loads per lane to cover HBM latency at 4 waves/SIMD.
// Also zeroes out[0] so k_pool can atomicAdd into it (saves a memset node).
__global__ __launch_bounds__(256) void k_embw(const float* __restrict__ emb,
                                              const float* __restrict__ W,
                                              float* __restrict__ embW,
                                              float* __restrict__ out) {
    if (blockIdx.x == 0 && threadIdx.x == 0) out[0] = 0.f;

    const int lane = threadIdx.x & 63;
    const int sub  = lane >> 4;   // which row of the quad this lane works on
    const int col  = lane & 15;   // 16-float chunk within the row

    // Per-lane register copy of W chunk: w[o][c] = W[o][col*16 + c*4 .. +3]
    float4 w[OUT][4];
#pragma unroll
    for (int o = 0; o < OUT; ++o)
#pragma unroll
        for (int c = 0; c < 4; ++c)
            w[o][c] = *(const float4*)(W + o * EMBED + col * 16 + c * 4);

    const int waveId = (int)((blockIdx.x * 256u + threadIdx.x) >> 6);
    const int nWaves = 1024 * 4;            // 4096 waves
    const int nQuad  = (VOCAB + 3) / 4;     // 12565 row-quads

#pragma unroll 2
    for (int q = waveId; q < nQuad; q += nWaves) {
        const int v = q * 4 + sub;
        float p[OUT] = {0.f, 0.f, 0.f, 0.f, 0.f};
        if (v < VOCAB) {
            const float* row = emb + (size_t)v * EMBED + col * 16;
#pragma unroll
            for (int c = 0; c < 4; ++c) {
                const float4 e = *(const float4*)(row + c * 4);
#pragma unroll
                for (int o = 0; o < OUT; ++o)
                    p[o] += e.x * w[o][c].x + e.y * w[o][c].y +
                            e.z * w[o][c].z + e.w * w[o][c].w;
            }
        }
        // Reduce within each 16-lane group (4 steps x 5 outputs).
#pragma unroll
        for (int o = 0; o < OUT; ++o) {
#pragma unroll
            for (int off = 8; off > 0; off >>= 1)
                p[o] += __shfl_down(p[o], off, 16);
        }
        if (col == 0 && v < VOCAB) {
            float* dst = embW + (size_t)v * PADO;   // 32 B-aligned
            *(float4*)dst = make_float4(p[0], p[1], p[2], p[3]);
            dst[4] = p[4];
        }
    }
}

// Kernel 2: one block per sample. int2 token loads (2 tokens/thread covers
// SEQ=512); aligned 32 B-stride gathers from L2-resident padded embW;
// logits -> log-softmax -> NLL; mean via one atomicAdd per block
// (512 adds, nondeterminism ~1e-6 << 3.2e-2 threshold).
__global__ __launch_bounds__(256) void k_pool(const int* __restrict__ x,
                                              const int* __restrict__ lengths,
                                              const int* __restrict__ y,
                                              const float* __restrict__ bias,
                                              const float* __restrict__ embW,
                                              float* __restrict__ out) {
    const int b   = blockIdx.x;
    const int len = lengths[b];
    const int tid = threadIdx.x;

    const int2 tk = ((const int2*)(x + (size_t)b * SEQ))[tid];

    float acc[OUT] = {0.f, 0.f, 0.f, 0.f, 0.f};
    if (2 * tid < len) {
        const float* r = embW + (size_t)tk.x * PADO;
        const float4 a = *(const float4*)r;
        const float a4 = r[4];
        acc[0] += a.x; acc[1] += a.y; acc[2] += a.z; acc[3] += a.w; acc[4] += a4;
    }
    if (2 * tid + 1 < len) {
        const float* r = embW + (size_t)tk.y * PADO;
        const float4 a = *(const float4*)r;
        const float a4 = r[4];
        acc[0] += a.x; acc[1] += a.y; acc[2] += a.z; acc[3] += a.w; acc[4] += a4;
    }

#pragma unroll
    for (int o = 0; o < OUT; ++o) {
#pragma unroll
        for (int off = 32; off > 0; off >>= 1)
            acc[o] += __shfl_down(acc[o], off, 64);
    }

    __shared__ float red[4][OUT];
    const int wave = tid >> 6;
    const int lane = tid & 63;
    if (lane == 0) {
#pragma unroll
        for (int o = 0; o < OUT; ++o) red[wave][o] = acc[o];
    }
    __syncthreads();

    if (tid == 0) {
        float logits[OUT];
        const float inv = 1.0f / (float)len;
#pragma unroll
        for (int o = 0; o < OUT; ++o)
            logits[o] = (red[0][o] + red[1][o] + red[2][o] + red[3][o]) * inv + bias[o];

        float m = logits[0];
#pragma unroll
        for (int o = 1; o < OUT; ++o) m = fmaxf(m, logits[o]);
        float sum = 0.f;
#pragma unroll
        for (int o = 0; o < OUT; ++o) sum += __expf(logits[o] - m);
        const float lse = m + __logf(sum);
        const float loss = lse - logits[y[b]];

        atomicAdd(out, loss * (1.0f / (float)BATCH));
    }
}

extern "C" void kernel_launch(void* const* d_in, const int* in_sizes, int n_in,
                              void* d_out, int out_size, void* d_ws, size_t ws_size,
                              hipStream_t stream) {
    const int*   x       = (const int*)d_in[0];
    const int*   lengths = (const int*)d_in[1];
    const int*   y       = (const int*)d_in[2];
    const float* emb     = (const float*)d_in[3];
    const float* W       = (const float*)d_in[4];
    const float* bias    = (const float*)d_in[5];

    float* embW = (float*)d_ws;   // VOCAB*PADO floats (~1.6 MB)
    float* outp = (float*)d_out;

    k_embw<<<1024, 256, 0, stream>>>(emb, W, embW, outp);
    k_pool<<<BATCH, 256, 0, stream>>>(x, lengths, y, bias, embW, outp);
}

// Round 6
// 102.041 us; speedup vs baseline: 1.5636x; 1.0404x over previous
//
#include <hip/hip_runtime.h>

#define VOCAB 50257
#define EMBED 256
#define OUT 5
#define BATCH 512
#define SEQ 512
#define PADO 8  // padded stride of embW rows (32 B -> aligned float4+float gathers)

// Kernel 1: embW[v][o] = dot(emb[v,:], W[o,:]).
// Persistent blocks (1024 = 4/CU). W lives in registers: lane holds the
// 16-float chunk (col = lane&15) of every W row -> loaded once per wave.
// Each wave processes 4 vocab rows per iteration: 16 lanes per row, so the
// cross-lane reduction is 4 shuffle steps (width 16) instead of 6 (width 64),
// and no LDS / __syncthreads at all.
// NOTE (round-5 post-mortem): keep the plain loop — `#pragma unroll 2` here
// measured +~2-5 us worse; loads are already latency-covered at 4 waves/SIMD.
__global__ __launch_bounds__(256) void k_embw(const float* __restrict__ emb,
                                              const float* __restrict__ W,
                                              float* __restrict__ embW) {
    const int lane = threadIdx.x & 63;
    const int sub  = lane >> 4;   // which row of the quad this lane works on
    const int col  = lane & 15;   // 16-float chunk within the row

    // Per-lane register copy of W chunk: w[o][c] = W[o][col*16 + c*4 .. +3]
    float4 w[OUT][4];
#pragma unroll
    for (int o = 0; o < OUT; ++o)
#pragma unroll
        for (int c = 0; c < 4; ++c)
            w[o][c] = *(const float4*)(W + o * EMBED + col * 16 + c * 4);

    const int waveId = (int)((blockIdx.x * 256u + threadIdx.x) >> 6);
    const int nWaves = 1024 * 4;            // 4096 waves
    const int nQuad  = (VOCAB + 3) / 4;     // 12565 row-quads

    for (int q = waveId; q < nQuad; q += nWaves) {
        const int v = q * 4 + sub;
        float p[OUT] = {0.f, 0.f, 0.f, 0.f, 0.f};
        if (v < VOCAB) {
            const float* row = emb + (size_t)v * EMBED + col * 16;
#pragma unroll
            for (int c = 0; c < 4; ++c) {
                const float4 e = *(const float4*)(row + c * 4);
#pragma unroll
                for (int o = 0; o < OUT; ++o)
                    p[o] += e.x * w[o][c].x + e.y * w[o][c].y +
                            e.z * w[o][c].z + e.w * w[o][c].w;
            }
        }
        // Reduce within each 16-lane group (4 steps x 5 outputs).
#pragma unroll
        for (int o = 0; o < OUT; ++o) {
#pragma unroll
            for (int off = 8; off > 0; off >>= 1)
                p[o] += __shfl_down(p[o], off, 16);
        }
        if (col == 0 && v < VOCAB) {
            float* dst = embW + (size_t)v * PADO;   // 32 B-aligned
            *(float4*)dst = make_float4(p[0], p[1], p[2], p[3]);
            dst[4] = p[4];
        }
    }
}

// Kernel 2: one block per sample. int2 token loads (2 tokens/thread covers
// SEQ=512 exactly); aligned 32 B-stride gathers from padded embW; then
// logits -> log-softmax -> per-sample NLL.
__global__ __launch_bounds__(256) void k_pool(const int* __restrict__ x,
                                              const int* __restrict__ lengths,
                                              const int* __restrict__ y,
                                              const float* __restrict__ bias,
                                              const float* __restrict__ embW,
                                              float* __restrict__ losses) {
    const int b   = blockIdx.x;
    const int len = lengths[b];
    const int tid = threadIdx.x;

    const int2 tk = ((const int2*)(x + (size_t)b * SEQ))[tid];

    float acc[OUT] = {0.f, 0.f, 0.f, 0.f, 0.f};
    if (2 * tid < len) {
        const float* r = embW + (size_t)tk.x * PADO;
        const float4 a = *(const float4*)r;
        const float a4 = r[4];
        acc[0] += a.x; acc[1] += a.y; acc[2] += a.z; acc[3] += a.w; acc[4] += a4;
    }
    if (2 * tid + 1 < len) {
        const float* r = embW + (size_t)tk.y * PADO;
        const float4 a = *(const float4*)r;
        const float a4 = r[4];
        acc[0] += a.x; acc[1] += a.y; acc[2] += a.z; acc[3] += a.w; acc[4] += a4;
    }

#pragma unroll
    for (int o = 0; o < OUT; ++o) {
#pragma unroll
        for (int off = 32; off > 0; off >>= 1)
            acc[o] += __shfl_down(acc[o], off, 64);
    }

    __shared__ float red[4][OUT];
    const int wave = tid >> 6;
    const int lane = tid & 63;
    if (lane == 0) {
#pragma unroll
        for (int o = 0; o < OUT; ++o) red[wave][o] = acc[o];
    }
    __syncthreads();

    if (tid == 0) {
        float logits[OUT];
        const float inv = 1.0f / (float)len;
#pragma unroll
        for (int o = 0; o < OUT; ++o)
            logits[o] = (red[0][o] + red[1][o] + red[2][o] + red[3][o]) * inv + bias[o];

        float m = logits[0];
#pragma unroll
        for (int o = 1; o < OUT; ++o) m = fmaxf(m, logits[o]);
        float sum = 0.f;
#pragma unroll
        for (int o = 0; o < OUT; ++o) sum += __expf(logits[o] - m);
        const float lse = m + __logf(sum);
        losses[b] = lse - logits[y[b]];
    }
}

// Kernel 3: deterministic mean over 512 per-sample losses.
__global__ __launch_bounds__(256) void k_reduce(const float* __restrict__ losses,
                                                float* __restrict__ out) {
    float v = losses[threadIdx.x] + losses[threadIdx.x + 256];
#pragma unroll
    for (int off = 32; off > 0; off >>= 1)
        v += __shfl_down(v, off, 64);
    __shared__ float red[4];
    if ((threadIdx.x & 63) == 0) red[threadIdx.x >> 6] = v;
    __syncthreads();
    if (threadIdx.x == 0)
        out[0] = (red[0] + red[1] + red[2] + red[3]) * (1.0f / (float)BATCH);
}

extern "C" void kernel_launch(void* const* d_in, const int* in_sizes, int n_in,
                              void* d_out, int out_size, void* d_ws, size_t ws_size,
                              hipStream_t stream) {
    const int*   x       = (const int*)d_in[0];
    const int*   lengths = (const int*)d_in[1];
    const int*   y       = (const int*)d_in[2];
    const float* emb     = (const float*)d_in[3];
    const float* W       = (const float*)d_in[4];
    const float* bias    = (const float*)d_in[5];

    float* embW   = (float*)d_ws;                     // VOCAB*PADO floats (~1.6 MB)
    float* losses = embW + (size_t)VOCAB * PADO;      // BATCH floats

    k_embw<<<1024, 256, 0, stream>>>(emb, W, embW);
    k_pool<<<BATCH, 256, 0, stream>>>(x, lengths, y, bias, embW, losses);
    k_reduce<<<1, 256, 0, stream>>>(losses, (float*)d_out);
}